// Round 2
// 774.701 us; speedup vs baseline: 1.1947x; 1.1947x over previous
//
#include <hip/hip_runtime.h>

typedef unsigned short u16;
typedef unsigned int   u32;
typedef __attribute__((ext_vector_type(8))) short short8;    // MFMA bf16 A/B frag
typedef __attribute__((ext_vector_type(8))) unsigned short u16x8;
typedef __attribute__((ext_vector_type(4))) float floatx4;

__device__ __forceinline__ float bf2f(u16 u) {
  union { u32 i; float f; } v; v.i = ((u32)u) << 16; return v.f;
}
__device__ __forceinline__ u16 f2bf(float f) {
  union { float f; u32 i; } v; v.f = f;
  u32 x = v.i;
  return (u16)((x + 0x7fffu + ((x >> 16) & 1u)) >> 16);  // RNE
}

// async global->LDS, 16B per lane. LDS dest = wave-uniform base + lane*16B.
__device__ __forceinline__ void gl_lds16(const u16* g, u16* l) {
  __builtin_amdgcn_global_load_lds(
      (const __attribute__((address_space(1))) void*)g,
      (__attribute__((address_space(3))) void*)l, 16, 0, 0);
}

// ---------------------------------------------------------------------------
// 0) convert the three weight matrices fp32 -> bf16 (row-major (N,K) kept).
__global__ __launch_bounds__(256) void k_cvtw(const float* __restrict__ qw,
    const float* __restrict__ kvw, const float* __restrict__ pw,
    u16* __restrict__ dst) {
  int i = blockIdx.x * 256 + threadIdx.x;          // 262144 total
  float v;
  if (i < 65536)        v = qw[i];
  else if (i < 196608)  v = kvw[i - 65536];
  else                  v = pw[i - 196608];
  dst[i] = f2bf(v);
}

// 1) bilinear 2x upsample of mask (8,1,64,64)->(8,1,128,128), half-pixel,
//    edge-clamped, times feat_mask.
__global__ __launch_bounds__(256) void k_interp(const float* __restrict__ mask,
                                                const float* __restrict__ fmask,
                                                float* __restrict__ E) {
  int idx = blockIdx.x * 256 + threadIdx.x;        // 131072
  int b = idx >> 14, y = (idx >> 7) & 127, x = idx & 127;
  int jy = y >> 1, jx = x >> 1;
  int y0, y1, x0, x1; float wy0, wx0;
  if (y & 1) { y0 = jy; y1 = jy + 1 > 63 ? 63 : jy + 1; wy0 = 0.75f; }
  else       { y0 = jy - 1 < 0 ? 0 : jy - 1; y1 = jy;    wy0 = 0.25f; }
  if (x & 1) { x0 = jx; x1 = jx + 1 > 63 ? 63 : jx + 1; wx0 = 0.75f; }
  else       { x0 = jx - 1 < 0 ? 0 : jx - 1; x1 = jx;    wx0 = 0.25f; }
  const float* mb = mask + (b << 12);
  float v0 = wx0 * mb[y0*64 + x0] + (1.f - wx0) * mb[y0*64 + x1];
  float v1 = wx0 * mb[y1*64 + x0] + (1.f - wx0) * mb[y1*64 + x1];
  float v  = wy0 * v0 + (1.f - wy0) * v1;
  E[idx] = v * fmask[y*128 + x];
}

// 2) per-window max of E >= 0.2 -> keep flag.
__global__ __launch_bounds__(64) void k_keep(const float* __restrict__ E,
                                             int* __restrict__ keepf) {
  int win = blockIdx.x;                       // 2048
  int lane = threadIdx.x;
  int b = win >> 8, wh = (win >> 4) & 15, ww = win & 15;
  int hi = lane >> 3, wi = lane & 7;
  float v = E[(b << 14) + (wh*8 + hi)*128 + ww*8 + wi];
  #pragma unroll
  for (int off = 32; off; off >>= 1) v = fmaxf(v, __shfl_xor(v, off, 64));
  if (lane == 0) keepf[win] = (v >= 0.2f) ? 1 : 0;
}

// 3) stage feat/pre_feat into (token, channel) row-major bf16 via LDS transpose.
// XCD-chunked swizzle: window w and w+1 (which share 128B feat cache lines for
// ww..ww+3) run consecutively on the SAME XCD -> 3/4 of line fetches L2-hit.
__global__ __launch_bounds__(256) void k_stage(const float* __restrict__ feat,
    const float* __restrict__ fmask, const float* __restrict__ pre,
    const float* __restrict__ pmask, const float* __restrict__ E,
    u16* __restrict__ Xw, u16* __restrict__ Tw) {
  __shared__ u16 lds[64 * 257];                // [pix][c], +1 pad
  int bid = blockIdx.x;
  int win = (bid & 7) * 256 + (bid >> 3);      // XCD k -> batch k, raster (wh,ww)
  int b = win >> 8, wh = (win >> 4) & 15, ww = win & 15;
  int h0 = wh * 8, w0 = ww * 8;
  int tid = threadIdx.x;
  int hi = tid & 7, cL = tid >> 3;             // cL in [0,32)
  int rowoff = (h0 + hi) * 128 + w0;
  float m[8];
  {
    floatx4 a = *(const floatx4*)(fmask + rowoff);
    floatx4 c = *(const floatx4*)(fmask + rowoff + 4);
    #pragma unroll
    for (int j = 0; j < 4; j++) { m[j] = a[j]; m[4 + j] = c[j]; }
  }
  #pragma unroll
  for (int i = 0; i < 8; i++) {
    int c = i * 32 + cL;
    size_t g = (((size_t)(b*256 + c)) << 14) + rowoff;
    floatx4 f0 = *(const floatx4*)(feat + g);
    floatx4 f1 = *(const floatx4*)(feat + g + 4);
    #pragma unroll
    for (int j = 0; j < 4; j++) {
      lds[(hi*8 + j)*257 + c]     = f2bf(f0[j] * m[j]);
      lds[(hi*8 + j + 4)*257 + c] = f2bf(f1[j] * m[4 + j]);
    }
  }
  __syncthreads();
  #pragma unroll
  for (int i = 0; i < 32; i++) {
    int pix = i*2 + (tid >> 7);
    int c = (tid & 127) * 2;
    u32 u = (u32)lds[pix*257 + c] | ((u32)lds[pix*257 + c + 1] << 16);
    *(u32*)(Xw + (((size_t)(win*64 + pix)) << 8) + c) = u;
  }
  __syncthreads();
  {
    floatx4 a = *(const floatx4*)(pmask + rowoff);
    floatx4 c = *(const floatx4*)(pmask + rowoff + 4);
    floatx4 e0 = *(const floatx4*)(E + (b << 14) + rowoff);
    floatx4 e1 = *(const floatx4*)(E + (b << 14) + rowoff + 4);
    #pragma unroll
    for (int j = 0; j < 4; j++) { m[j] = a[j] * e0[j]; m[4 + j] = c[j] * e1[j]; }
  }
  #pragma unroll
  for (int i = 0; i < 8; i++) {
    int c = i * 32 + cL;
    size_t g = (((size_t)(b*256 + c)) << 14) + rowoff;
    floatx4 f0 = *(const floatx4*)(pre + g);
    floatx4 f1 = *(const floatx4*)(pre + g + 4);
    #pragma unroll
    for (int j = 0; j < 4; j++) {
      lds[(hi*8 + j)*257 + c]     = f2bf(f0[j] * m[j]);
      lds[(hi*8 + j + 4)*257 + c] = f2bf(f1[j] * m[4 + j]);
    }
  }
  __syncthreads();
  #pragma unroll
  for (int i = 0; i < 32; i++) {
    int pix = i*2 + (tid >> 7);
    int c = (tid & 127) * 2;
    u32 u = (u32)lds[pix*257 + c] | ((u32)lds[pix*257 + c + 1] << 16);
    *(u32*)(Tw + (((size_t)(win*64 + pix)) << 8) + c) = u;
  }
}

// ---------------------------------------------------------------------------
// m97-style 128x128 GEMM: C[M,256] = A[M,256] @ W[256,256]^T (+bias).
// BK=32, global_load_lds(16B) staging, 4 waves x 64x64 quadrants.
__global__ __launch_bounds__(256) void k_gemm128n(const u16* __restrict__ A,
    const u16* __restrict__ W, const float* __restrict__ bias,
    u16* __restrict__ C) {
  __shared__ u16 As[128 * 32], Ws[128 * 32];   // 8 KB each
  int bi = blockIdx.x;                          // 2048
  int xcd = bi & 7, t = bi >> 3;
  int y = t & 1, xg = t >> 1;                   // Ny = 2
  int row0 = (xg * 8 + xcd) << 7, col0 = y << 7;
  int wv = threadIdx.x >> 6, lane = threadIdx.x & 63;
  int qq = lane >> 4, l = lane & 15;
  int srow = lane >> 2, skoff = (lane & 3) << 3;
  const u16* Ag = A + (size_t)(row0 + wv*32 + srow) * 256 + skoff;
  const u16* Wg = W + (size_t)(col0 + wv*32 + srow) * 256 + skoff;
  u16* AsW = As + (wv*32) * 32;
  u16* WsW = Ws + (wv*32) * 32;
  int wr = wv >> 1, wc = wv & 1;
  int r0 = wr * 64, c0 = wc * 64;
  floatx4 z = {0.f, 0.f, 0.f, 0.f};
  floatx4 acc[4][4];
  #pragma unroll
  for (int a = 0; a < 4; a++)
    #pragma unroll
    for (int b = 0; b < 4; b++) acc[a][b] = z;
  for (int kb = 0; kb < 256; kb += 32) {
    __syncthreads();
    gl_lds16(Ag + kb,            AsW);
    gl_lds16(Ag + kb + 16*256,   AsW + 16*32);
    gl_lds16(Wg + kb,            WsW);
    gl_lds16(Wg + kb + 16*256,   WsW + 16*32);
    __syncthreads();
    short8 af[4], wf[4];
    #pragma unroll
    for (int tn = 0; tn < 4; tn++)
      af[tn] = *(const short8*)&As[(r0 + tn*16 + l)*32 + qq*8];
    #pragma unroll
    for (int tm = 0; tm < 4; tm++)
      wf[tm] = *(const short8*)&Ws[(c0 + tm*16 + l)*32 + qq*8];
    #pragma unroll
    for (int tn = 0; tn < 4; tn++)
      #pragma unroll
      for (int tm = 0; tm < 4; tm++)
        acc[tn][tm] = __builtin_amdgcn_mfma_f32_16x16x32_bf16(af[tn], wf[tm], acc[tn][tm], 0, 0, 0);
  }
  #pragma unroll
  for (int tm = 0; tm < 4; tm++) {
    int col = col0 + c0 + tm*16 + l;
    float bv = bias ? bias[col] : 0.f;
    #pragma unroll
    for (int tn = 0; tn < 4; tn++) {
      #pragma unroll
      for (int r = 0; r < 4; r++) {
        int row = row0 + r0 + tn*16 + qq*4 + r;   // C/D map: col=lane&15, row=quad*4+reg
        C[(size_t)row * 256 + col] = f2bf(acc[tn][tm][r] + bv);
      }
    }
  }
}

// KV variant: N=512 (Ny=4), plain row-major output KV[131072][512]
// (K in cols 0..255, V in cols 256..511). No transposed scatter: coalescing
// identical to the N-variant; attn transposes its own 8KB V tile via LDS.
__global__ __launch_bounds__(256) void k_gemm128kv(const u16* __restrict__ A,
    const u16* __restrict__ W, u16* __restrict__ Cb) {
  __shared__ u16 As[128 * 32], Ws[128 * 32];
  int bi = blockIdx.x;                          // 4096
  int xcd = bi & 7, t = bi >> 3;
  int y = t & 3, xg = t >> 2;                   // Ny = 4
  int row0 = (xg * 8 + xcd) << 7, col0 = y << 7;
  int wv = threadIdx.x >> 6, lane = threadIdx.x & 63;
  int qq = lane >> 4, l = lane & 15;
  int srow = lane >> 2, skoff = (lane & 3) << 3;
  const u16* Ag = A + (size_t)(row0 + wv*32 + srow) * 256 + skoff;
  const u16* Wg = W + (size_t)(col0 + wv*32 + srow) * 256 + skoff;
  u16* AsW = As + (wv*32) * 32;
  u16* WsW = Ws + (wv*32) * 32;
  int wr = wv >> 1, wc = wv & 1;
  int r0 = wr * 64, c0 = wc * 64;
  floatx4 z = {0.f, 0.f, 0.f, 0.f};
  floatx4 acc[4][4];
  #pragma unroll
  for (int a = 0; a < 4; a++)
    #pragma unroll
    for (int b = 0; b < 4; b++) acc[a][b] = z;
  for (int kb = 0; kb < 256; kb += 32) {
    __syncthreads();
    gl_lds16(Ag + kb,            AsW);
    gl_lds16(Ag + kb + 16*256,   AsW + 16*32);
    gl_lds16(Wg + kb,            WsW);
    gl_lds16(Wg + kb + 16*256,   WsW + 16*32);
    __syncthreads();
    short8 af[4], wf[4];
    #pragma unroll
    for (int tn = 0; tn < 4; tn++)
      af[tn] = *(const short8*)&As[(r0 + tn*16 + l)*32 + qq*8];
    #pragma unroll
    for (int tm = 0; tm < 4; tm++)
      wf[tm] = *(const short8*)&Ws[(c0 + tm*16 + l)*32 + qq*8];
    #pragma unroll
    for (int tn = 0; tn < 4; tn++)
      #pragma unroll
      for (int tm = 0; tm < 4; tm++)
        acc[tn][tm] = __builtin_amdgcn_mfma_f32_16x16x32_bf16(af[tn], wf[tm], acc[tn][tm], 0, 0, 0);
  }
  #pragma unroll
  for (int tm = 0; tm < 4; tm++) {
    int col = col0 + c0 + tm*16 + l;
    #pragma unroll
    for (int tn = 0; tn < 4; tn++) {
      #pragma unroll
      for (int r = 0; r < 4; r++) {
        int row = row0 + r0 + tn*16 + qq*4 + r;
        Cb[(size_t)row * 512 + col] = f2bf(acc[tn][tm][r]);
      }
    }
  }
}

// 6) per-window cross attention. block = window (256 thr), wave = head.
// Waves touch only their own head's LDS slice -> no __syncthreads at all.
// V is staged row-major into LDS (coalesced b128 writes), transposed frags are
// pulled to registers BEFORE the same LDS slice is reused for P.
__global__ __launch_bounds__(256) void k_attn(const u16* __restrict__ Q,
    const u16* __restrict__ KV, u16* __restrict__ O) {
  __shared__ __align__(16) u16 buf[4][64 * 72];  // per-head: V rows, then P
  int win = blockIdx.x;
  int head = threadIdx.x >> 6, lane = threadIdx.x & 63;
  int qq = lane >> 4, l = lane & 15;
  const u16* Qh = Q  + (size_t)win * 64 * 256 + head * 64;
  const u16* Kh = KV + (size_t)win * 64 * 512 + head * 64;
  const u16* Vh = Kh + 256;
  u16* hb = &buf[head][0];
  // stage V rows: hb[m*72 + d] = V[m][d]  (b128, coalesced, wave-local)
  {
    int mg = lane >> 3, dg = lane & 7;
    #pragma unroll
    for (int i = 0; i < 8; i++) {
      int m = i*8 + mg;
      *(u16x8*)(hb + m*72 + dg*8) = *(const u16x8*)(Vh + (size_t)m*512 + dg*8);
    }
  }
  // transposed V frags -> regs: vf[kbh][td][j] = V[kbh*32+qq*8+j][td*16+l]
  short8 vf[2][4];
  #pragma unroll
  for (int kbh = 0; kbh < 2; kbh++)
    #pragma unroll
    for (int td = 0; td < 4; td++)
      #pragma unroll
      for (int j = 0; j < 8; j++)
        ((u16*)&vf[kbh][td])[j] = hb[(kbh*32 + qq*8 + j)*72 + td*16 + l];
  // QK^T
  floatx4 z = {0.f, 0.f, 0.f, 0.f};
  floatx4 s[4][4];
  #pragma unroll
  for (int a = 0; a < 4; a++)
    #pragma unroll
    for (int b = 0; b < 4; b++) s[a][b] = z;
  #pragma unroll
  for (int kb = 0; kb < 64; kb += 32) {
    short8 af[4], bf[4];
    #pragma unroll
    for (int tn = 0; tn < 4; tn++)
      af[tn] = *(const short8*)(Qh + (size_t)(tn*16 + l) * 256 + kb + qq*8);
    #pragma unroll
    for (int tm = 0; tm < 4; tm++)
      bf[tm] = *(const short8*)(Kh + (size_t)(tm*16 + l) * 512 + kb + qq*8);
    #pragma unroll
    for (int tn = 0; tn < 4; tn++)
      #pragma unroll
      for (int tm = 0; tm < 4; tm++)
        s[tn][tm] = __builtin_amdgcn_mfma_f32_16x16x32_bf16(af[tn], bf[tm], s[tn][tm], 0, 0, 0);
  }
  // softmax rows (over m = tm*16+l, in-thread over tm, cross-lane over l)
  #pragma unroll
  for (int tn = 0; tn < 4; tn++) {
    #pragma unroll
    for (int r = 0; r < 4; r++) {
      float v[4];
      #pragma unroll
      for (int tm = 0; tm < 4; tm++) v[tm] = s[tn][tm][r] * 0.125f;  // hd^-0.5
      float mx = -3.0e38f;
      #pragma unroll
      for (int tm = 0; tm < 4; tm++) mx = fmaxf(mx, v[tm]);
      #pragma unroll
      for (int off = 1; off < 16; off <<= 1) mx = fmaxf(mx, __shfl_xor(mx, off, 64));
      float p0[4], sum = 0.f;
      #pragma unroll
      for (int tm = 0; tm < 4; tm++) { p0[tm] = __expf(v[tm] - mx); sum += p0[tm]; }
      #pragma unroll
      for (int off = 1; off < 16; off <<= 1) sum += __shfl_xor(sum, off, 64);
      float inv = 1.0f / sum;
      int n = tn*16 + qq*4 + r;
      #pragma unroll
      for (int tm = 0; tm < 4; tm++)
        hb[n*72 + tm*16 + l] = f2bf(p0[tm] * inv);   // overwrites V rows (frags in regs)
    }
  }
  // PV
  floatx4 o[4][4];
  #pragma unroll
  for (int a = 0; a < 4; a++)
    #pragma unroll
    for (int b = 0; b < 4; b++) o[a][b] = z;
  #pragma unroll
  for (int kbh = 0; kbh < 2; kbh++) {
    short8 af[4];
    #pragma unroll
    for (int tn = 0; tn < 4; tn++)
      af[tn] = *(const short8*)(hb + (tn*16 + l)*72 + kbh*32 + qq*8);
    #pragma unroll
    for (int tn = 0; tn < 4; tn++)
      #pragma unroll
      for (int td = 0; td < 4; td++)
        o[tn][td] = __builtin_amdgcn_mfma_f32_16x16x32_bf16(af[tn], vf[kbh][td], o[tn][td], 0, 0, 0);
  }
  #pragma unroll
  for (int tn = 0; tn < 4; tn++)
    #pragma unroll
    for (int td = 0; td < 4; td++)
      #pragma unroll
      for (int r = 0; r < 4; r++)
        O[(size_t)(win*64 + tn*16 + qq*4 + r) * 256 + head*64 + td*16 + l] =
            f2bf(o[tn][td][r]);
}

// 7) window_reverse + keep-zeroing + residual add -> xbuf fp32, fused BN stats.
// Same XCD-chunked swizzle as k_stage (feat re-read + partial-line out writes
// share 128B lines across 4 adjacent windows).
__global__ __launch_bounds__(256) void k_reverse(const u16* __restrict__ heat,
    const int* __restrict__ keepf, const float* __restrict__ feat,
    const float* __restrict__ fmask, float* __restrict__ xbuf,
    float* __restrict__ stats) {
  __shared__ u16 lds[64 * 257];
  int bid = blockIdx.x;
  int win = (bid & 7) * 256 + (bid >> 3);
  int b = win >> 8, wh = (win >> 4) & 15, ww = win & 15;
  int h0 = wh * 8, w0 = ww * 8;
  int tid = threadIdx.x;
  float kp = keepf[win] ? 1.f : 0.f;
  #pragma unroll
  for (int i = 0; i < 32; i++) {
    int pix = i*2 + (tid >> 7);
    int c = (tid & 127) * 2;
    u32 u = *(const u32*)(heat + (((size_t)(win*64 + pix)) << 8) + c);
    lds[pix*257 + c]     = (u16)(u & 0xffffu);
    lds[pix*257 + c + 1] = (u16)(u >> 16);
  }
  __syncthreads();
  int hi = tid & 7, cL = tid >> 3;
  int rowoff = (h0 + hi) * 128 + w0;
  float m[8];
  {
    floatx4 a = *(const floatx4*)(fmask + rowoff);
    floatx4 c = *(const floatx4*)(fmask + rowoff + 4);
    #pragma unroll
    for (int j = 0; j < 4; j++) { m[j] = a[j]; m[4 + j] = c[j]; }
  }
  #pragma unroll
  for (int i = 0; i < 8; i++) {
    int c = i * 32 + cL;
    size_t goff = (((size_t)(b*256 + c)) << 14) + rowoff;
    floatx4 f0 = *(const floatx4*)(feat + goff);
    floatx4 f1 = *(const floatx4*)(feat + goff + 4);
    floatx4 o0, o1;
    float ls = 0.f, lss = 0.f;
    #pragma unroll
    for (int j = 0; j < 4; j++) {
      o0[j] = kp * bf2f(lds[(hi*8 + j)*257 + c])     + f0[j] * m[j];
      o1[j] = kp * bf2f(lds[(hi*8 + j + 4)*257 + c]) + f1[j] * m[4 + j];
      ls += o0[j] + o1[j];
      lss += o0[j]*o0[j] + o1[j]*o1[j];
    }
    *(floatx4*)(xbuf + goff)     = o0;
    *(floatx4*)(xbuf + goff + 4) = o1;
    // reduce the 8 pixel-rows (hi) of this channel: lanes differ in bits 0..2
    #pragma unroll
    for (int off = 1; off < 8; off <<= 1) {
      ls  += __shfl_xor(ls,  off, 64);
      lss += __shfl_xor(lss, off, 64);
    }
    if (hi == 0) {
      atomicAdd(&stats[c],       ls);
      atomicAdd(&stats[256 + c], lss);
    }
  }
}

// 9) fold mean/var/gamma/beta into per-channel scale+shift.
__global__ void k_scaleshift(const float* __restrict__ stats,
                             const float* __restrict__ gamma,
                             const float* __restrict__ beta,
                             float* __restrict__ scsh) {
  int c = threadIdx.x;
  const float invN = 1.0f / 131072.0f;
  float mean = stats[c] * invN;
  float var  = stats[256 + c] * invN - mean * mean;
  float sc = gamma[c] * rsqrtf(var + 1e-5f);
  scsh[c] = sc;
  scsh[256 + c] = beta[c] - mean * sc;
}

// 10) normalize in-place (xbuf == out, fp32).
__global__ __launch_bounds__(256) void k_norm(float* __restrict__ xbuf,
                                              const float* __restrict__ scsh) {
  size_t e = ((size_t)blockIdx.x * 256 + threadIdx.x) * 4;
  int c = (int)((e >> 14) & 255);
  float sc = scsh[c], sh = scsh[256 + c];
  floatx4 v4 = *(const floatx4*)(xbuf + e);
  #pragma unroll
  for (int j = 0; j < 4; j++) v4[j] = v4[j] * sc + sh;
  *(floatx4*)(xbuf + e) = v4;
}

extern "C" void kernel_launch(void* const* d_in, const int* in_sizes, int n_in,
                              void* d_out, int out_size, void* d_ws, size_t ws_size,
                              hipStream_t stream) {
  (void)in_sizes; (void)n_in; (void)out_size; (void)ws_size;
  const float* pre    = (const float*)d_in[0];
  const float* pmask  = (const float*)d_in[1];
  const float* feat   = (const float*)d_in[2];
  const float* fmask  = (const float*)d_in[3];
  const float* maskin = (const float*)d_in[4];
  const float* q_w    = (const float*)d_in[5];
  const float* kv_w   = (const float*)d_in[6];
  const float* proj_w = (const float*)d_in[7];
  const float* proj_b = (const float*)d_in[8];
  const float* gamma  = (const float*)d_in[9];
  const float* beta   = (const float*)d_in[10];
  float* out = (float*)d_out;

  const size_t NE = 33554432;                 // 131072 x 256
  u16* Xw = (u16*)d_ws;                       // staging X; later attention O
  u16* Tw = Xw + NE;                          // staging T; later heat
  u16* Qb = Tw + NE;                          // Q
  u16* KV = Qb + NE;                          // row-major [131072][512]: K | V
  u16* Wb = KV + 2*NE;                        // bf16 weights: q(65536) kv(131072) proj(65536)
  float* E     = (float*)(Wb + 262144);       // 131072 floats
  int*   keepf = (int*)(E + 131072);          // 2048 ints
  float* stats = (float*)(keepf + 2048);      // sum[256], sumsq[256]
  float* scsh  = stats + 512;                 // scale[256], shift[256]

  hipMemsetAsync(stats, 0, 2048, stream);
  k_cvtw<<<1024, 256, 0, stream>>>(q_w, kv_w, proj_w, Wb);
  k_interp<<<512, 256, 0, stream>>>(maskin, fmask, E);
  k_keep<<<2048, 64, 0, stream>>>(E, keepf);
  k_stage<<<2048, 256, 0, stream>>>(feat, fmask, pre, pmask, E, Xw, Tw);
  k_gemm128n<<<2048, 256, 0, stream>>>(Xw, Wb, nullptr, Qb);
  k_gemm128kv<<<4096, 256, 0, stream>>>(Tw, Wb + 65536, KV);
  k_attn<<<2048, 256, 0, stream>>>(Qb, KV, Xw /*O (Xw dead)*/);
  k_gemm128n<<<2048, 256, 0, stream>>>(Xw /*O*/, Wb + 196608, proj_b, Tw /*heat*/);
  k_reverse<<<2048, 256, 0, stream>>>(Tw /*heat*/, keepf, feat, fmask,
                                      out /*xbuf fp32*/, stats);
  k_scaleshift<<<1, 256, 0, stream>>>(stats, gamma, beta, scsh);
  k_norm<<<32768, 256, 0, stream>>>(out, scsh);
}

// Round 3
// 753.065 us; speedup vs baseline: 1.2291x; 1.0287x over previous
//
#include <hip/hip_runtime.h>

typedef unsigned short u16;
typedef unsigned int   u32;
typedef __attribute__((ext_vector_type(8))) short short8;    // MFMA bf16 A/B frag
typedef __attribute__((ext_vector_type(8))) unsigned short u16x8;
typedef __attribute__((ext_vector_type(4))) float floatx4;

__device__ __forceinline__ float bf2f(u16 u) {
  union { u32 i; float f; } v; v.i = ((u32)u) << 16; return v.f;
}
__device__ __forceinline__ u16 f2bf(float f) {
  union { float f; u32 i; } v; v.f = f;
  u32 x = v.i;
  return (u16)((x + 0x7fffu + ((x >> 16) & 1u)) >> 16);  // RNE
}

// async global->LDS, 16B per lane. LDS dest = wave-uniform base + lane*16B.
__device__ __forceinline__ void gl_lds16(const u16* g, u16* l) {
  __builtin_amdgcn_global_load_lds(
      (const __attribute__((address_space(1))) void*)g,
      (__attribute__((address_space(3))) void*)l, 16, 0, 0);
}

__device__ __forceinline__ void ld2(const float* p, floatx4& v0, floatx4& v1) {
  v0 = *(const floatx4*)p; v1 = *(const floatx4*)(p + 4);
}

// ---------------------------------------------------------------------------
// 0) convert the three weight matrices fp32 -> bf16 (row-major (N,K) kept).
__global__ __launch_bounds__(256) void k_cvtw(const float* __restrict__ qw,
    const float* __restrict__ kvw, const float* __restrict__ pw,
    u16* __restrict__ dst) {
  int i = blockIdx.x * 256 + threadIdx.x;          // 262144 total
  float v;
  if (i < 65536)        v = qw[i];
  else if (i < 196608)  v = kvw[i - 65536];
  else                  v = pw[i - 196608];
  dst[i] = f2bf(v);
}

// 1) bilinear 2x upsample of mask (8,1,64,64)->(8,1,128,128), half-pixel,
//    edge-clamped, times feat_mask.
__global__ __launch_bounds__(256) void k_interp(const float* __restrict__ mask,
                                                const float* __restrict__ fmask,
                                                float* __restrict__ E) {
  int idx = blockIdx.x * 256 + threadIdx.x;        // 131072
  int b = idx >> 14, y = (idx >> 7) & 127, x = idx & 127;
  int jy = y >> 1, jx = x >> 1;
  int y0, y1, x0, x1; float wy0, wx0;
  if (y & 1) { y0 = jy; y1 = jy + 1 > 63 ? 63 : jy + 1; wy0 = 0.75f; }
  else       { y0 = jy - 1 < 0 ? 0 : jy - 1; y1 = jy;    wy0 = 0.25f; }
  if (x & 1) { x0 = jx; x1 = jx + 1 > 63 ? 63 : jx + 1; wx0 = 0.75f; }
  else       { x0 = jx - 1 < 0 ? 0 : jx - 1; x1 = jx;    wx0 = 0.25f; }
  const float* mb = mask + (b << 12);
  float v0 = wx0 * mb[y0*64 + x0] + (1.f - wx0) * mb[y0*64 + x1];
  float v1 = wx0 * mb[y1*64 + x0] + (1.f - wx0) * mb[y1*64 + x1];
  float v  = wy0 * v0 + (1.f - wy0) * v1;
  E[idx] = v * fmask[y*128 + x];
}

// 2) per-window max of E >= 0.2 -> keep flag.
__global__ __launch_bounds__(64) void k_keep(const float* __restrict__ E,
                                             int* __restrict__ keepf) {
  int win = blockIdx.x;                       // 2048
  int lane = threadIdx.x;
  int b = win >> 8, wh = (win >> 4) & 15, ww = win & 15;
  int hi = lane >> 3, wi = lane & 7;
  float v = E[(b << 14) + (wh*8 + hi)*128 + ww*8 + wi];
  #pragma unroll
  for (int off = 32; off; off >>= 1) v = fmaxf(v, __shfl_xor(v, off, 64));
  if (lane == 0) keepf[win] = (v >= 0.2f) ? 1 : 0;
}

// store 8 masked+converted values for channel c into the transpose LDS tile
__device__ __forceinline__ void stage_st(u16* lds, int hi, int c,
    const float* mk, floatx4 v0, floatx4 v1) {
  #pragma unroll
  for (int j = 0; j < 4; j++) {
    lds[(hi*8 + j)*257 + c]     = f2bf(v0[j] * mk[j]);
    lds[(hi*8 + j + 4)*257 + c] = f2bf(v1[j] * mk[4 + j]);
  }
}

// 3) stage feat/pre_feat into (token, channel) row-major bf16 via LDS transpose.
// XCD-chunked swizzle for L2 line sharing; 3-deep software pipeline on the
// scattered channel-plane loads (latency was the limiter, not BW).
__global__ __launch_bounds__(256) void k_stage(const float* __restrict__ feat,
    const float* __restrict__ fmask, const float* __restrict__ pre,
    const float* __restrict__ pmask, const float* __restrict__ E,
    u16* __restrict__ Xw, u16* __restrict__ Tw) {
  __shared__ u16 lds[64 * 257];                // [pix][c], +1 pad
  int bid = blockIdx.x;
  int win = (bid & 7) * 256 + (bid >> 3);      // XCD k -> batch k, raster (wh,ww)
  int b = win >> 8, wh = (win >> 4) & 15, ww = win & 15;
  int h0 = wh * 8, w0 = ww * 8;
  int tid = threadIdx.x;
  int hi = tid & 7, cL = tid >> 3;             // cL in [0,32)
  int rowoff = (h0 + hi) * 128 + w0;
  size_t base = (((size_t)(b*256 + cL)) << 14) + rowoff;   // + i*(1<<19) per ch-grp
  float mk[8];
  {
    floatx4 a = *(const floatx4*)(fmask + rowoff);
    floatx4 c = *(const floatx4*)(fmask + rowoff + 4);
    #pragma unroll
    for (int j = 0; j < 4; j++) { mk[j] = a[j]; mk[4 + j] = c[j]; }
  }
  {
    const float* fp = feat + base;
    floatx4 a0,a1,b0,b1,c0,c1;
    ld2(fp,                    a0, a1);
    ld2(fp + (1ull<<19),       b0, b1);
    ld2(fp + (2ull<<19),       c0, c1);
    stage_st(lds, hi, cL,       mk, a0, a1);  ld2(fp + (3ull<<19), a0, a1);
    stage_st(lds, hi, 32 + cL,  mk, b0, b1);  ld2(fp + (4ull<<19), b0, b1);
    stage_st(lds, hi, 64 + cL,  mk, c0, c1);  ld2(fp + (5ull<<19), c0, c1);
    stage_st(lds, hi, 96 + cL,  mk, a0, a1);  ld2(fp + (6ull<<19), a0, a1);
    stage_st(lds, hi, 128 + cL, mk, b0, b1);  ld2(fp + (7ull<<19), b0, b1);
    stage_st(lds, hi, 160 + cL, mk, c0, c1);
    stage_st(lds, hi, 192 + cL, mk, a0, a1);
    stage_st(lds, hi, 224 + cL, mk, b0, b1);
  }
  __syncthreads();
  #pragma unroll
  for (int i = 0; i < 32; i++) {
    int pix = i*2 + (tid >> 7);
    int c = (tid & 127) * 2;
    u32 u = (u32)lds[pix*257 + c] | ((u32)lds[pix*257 + c + 1] << 16);
    *(u32*)(Xw + (((size_t)(win*64 + pix)) << 8) + c) = u;
  }
  __syncthreads();
  {
    floatx4 a = *(const floatx4*)(pmask + rowoff);
    floatx4 c = *(const floatx4*)(pmask + rowoff + 4);
    floatx4 e0 = *(const floatx4*)(E + (b << 14) + rowoff);
    floatx4 e1 = *(const floatx4*)(E + (b << 14) + rowoff + 4);
    #pragma unroll
    for (int j = 0; j < 4; j++) { mk[j] = a[j] * e0[j]; mk[4 + j] = c[j] * e1[j]; }
  }
  {
    const float* fp = pre + base;
    floatx4 a0,a1,b0,b1,c0,c1;
    ld2(fp,                    a0, a1);
    ld2(fp + (1ull<<19),       b0, b1);
    ld2(fp + (2ull<<19),       c0, c1);
    stage_st(lds, hi, cL,       mk, a0, a1);  ld2(fp + (3ull<<19), a0, a1);
    stage_st(lds, hi, 32 + cL,  mk, b0, b1);  ld2(fp + (4ull<<19), b0, b1);
    stage_st(lds, hi, 64 + cL,  mk, c0, c1);  ld2(fp + (5ull<<19), c0, c1);
    stage_st(lds, hi, 96 + cL,  mk, a0, a1);  ld2(fp + (6ull<<19), a0, a1);
    stage_st(lds, hi, 128 + cL, mk, b0, b1);  ld2(fp + (7ull<<19), b0, b1);
    stage_st(lds, hi, 160 + cL, mk, c0, c1);
    stage_st(lds, hi, 192 + cL, mk, a0, a1);
    stage_st(lds, hi, 224 + cL, mk, b0, b1);
  }
  __syncthreads();
  #pragma unroll
  for (int i = 0; i < 32; i++) {
    int pix = i*2 + (tid >> 7);
    int c = (tid & 127) * 2;
    u32 u = (u32)lds[pix*257 + c] | ((u32)lds[pix*257 + c + 1] << 16);
    *(u32*)(Tw + (((size_t)(win*64 + pix)) << 8) + c) = u;
  }
}

// ---------------------------------------------------------------------------
// m97-style 128x128 GEMM: C[M,256] = A[M,256] @ W[256,256]^T (+bias).
// BK=32, global_load_lds(16B) staging, 4 waves x 64x64 quadrants.
__global__ __launch_bounds__(256) void k_gemm128n(const u16* __restrict__ A,
    const u16* __restrict__ W, const float* __restrict__ bias,
    u16* __restrict__ C) {
  __shared__ u16 As[128 * 32], Ws[128 * 32];   // 8 KB each
  int bi = blockIdx.x;                          // 2048
  int xcd = bi & 7, t = bi >> 3;
  int y = t & 1, xg = t >> 1;                   // Ny = 2
  int row0 = (xg * 8 + xcd) << 7, col0 = y << 7;
  int wv = threadIdx.x >> 6, lane = threadIdx.x & 63;
  int qq = lane >> 4, l = lane & 15;
  int srow = lane >> 2, skoff = (lane & 3) << 3;
  const u16* Ag = A + (size_t)(row0 + wv*32 + srow) * 256 + skoff;
  const u16* Wg = W + (size_t)(col0 + wv*32 + srow) * 256 + skoff;
  u16* AsW = As + (wv*32) * 32;
  u16* WsW = Ws + (wv*32) * 32;
  int wr = wv >> 1, wc = wv & 1;
  int r0 = wr * 64, c0 = wc * 64;
  floatx4 z = {0.f, 0.f, 0.f, 0.f};
  floatx4 acc[4][4];
  #pragma unroll
  for (int a = 0; a < 4; a++)
    #pragma unroll
    for (int b = 0; b < 4; b++) acc[a][b] = z;
  for (int kb = 0; kb < 256; kb += 32) {
    __syncthreads();
    gl_lds16(Ag + kb,            AsW);
    gl_lds16(Ag + kb + 16*256,   AsW + 16*32);
    gl_lds16(Wg + kb,            WsW);
    gl_lds16(Wg + kb + 16*256,   WsW + 16*32);
    __syncthreads();
    short8 af[4], wf[4];
    #pragma unroll
    for (int tn = 0; tn < 4; tn++)
      af[tn] = *(const short8*)&As[(r0 + tn*16 + l)*32 + qq*8];
    #pragma unroll
    for (int tm = 0; tm < 4; tm++)
      wf[tm] = *(const short8*)&Ws[(c0 + tm*16 + l)*32 + qq*8];
    #pragma unroll
    for (int tn = 0; tn < 4; tn++)
      #pragma unroll
      for (int tm = 0; tm < 4; tm++)
        acc[tn][tm] = __builtin_amdgcn_mfma_f32_16x16x32_bf16(af[tn], wf[tm], acc[tn][tm], 0, 0, 0);
  }
  #pragma unroll
  for (int tm = 0; tm < 4; tm++) {
    int col = col0 + c0 + tm*16 + l;
    float bv = bias ? bias[col] : 0.f;
    #pragma unroll
    for (int tn = 0; tn < 4; tn++) {
      #pragma unroll
      for (int r = 0; r < 4; r++) {
        int row = row0 + r0 + tn*16 + qq*4 + r;   // C/D map: col=lane&15, row=quad*4+reg
        C[(size_t)row * 256 + col] = f2bf(acc[tn][tm][r] + bv);
      }
    }
  }
}

// KV variant: N=512 (Ny=4), plain row-major output KV[131072][512]
// (K in cols 0..255, V in cols 256..511).
__global__ __launch_bounds__(256) void k_gemm128kv(const u16* __restrict__ A,
    const u16* __restrict__ W, u16* __restrict__ Cb) {
  __shared__ u16 As[128 * 32], Ws[128 * 32];
  int bi = blockIdx.x;                          // 4096
  int xcd = bi & 7, t = bi >> 3;
  int y = t & 3, xg = t >> 2;                   // Ny = 4
  int row0 = (xg * 8 + xcd) << 7, col0 = y << 7;
  int wv = threadIdx.x >> 6, lane = threadIdx.x & 63;
  int qq = lane >> 4, l = lane & 15;
  int srow = lane >> 2, skoff = (lane & 3) << 3;
  const u16* Ag = A + (size_t)(row0 + wv*32 + srow) * 256 + skoff;
  const u16* Wg = W + (size_t)(col0 + wv*32 + srow) * 256 + skoff;
  u16* AsW = As + (wv*32) * 32;
  u16* WsW = Ws + (wv*32) * 32;
  int wr = wv >> 1, wc = wv & 1;
  int r0 = wr * 64, c0 = wc * 64;
  floatx4 z = {0.f, 0.f, 0.f, 0.f};
  floatx4 acc[4][4];
  #pragma unroll
  for (int a = 0; a < 4; a++)
    #pragma unroll
    for (int b = 0; b < 4; b++) acc[a][b] = z;
  for (int kb = 0; kb < 256; kb += 32) {
    __syncthreads();
    gl_lds16(Ag + kb,            AsW);
    gl_lds16(Ag + kb + 16*256,   AsW + 16*32);
    gl_lds16(Wg + kb,            WsW);
    gl_lds16(Wg + kb + 16*256,   WsW + 16*32);
    __syncthreads();
    short8 af[4], wf[4];
    #pragma unroll
    for (int tn = 0; tn < 4; tn++)
      af[tn] = *(const short8*)&As[(r0 + tn*16 + l)*32 + qq*8];
    #pragma unroll
    for (int tm = 0; tm < 4; tm++)
      wf[tm] = *(const short8*)&Ws[(c0 + tm*16 + l)*32 + qq*8];
    #pragma unroll
    for (int tn = 0; tn < 4; tn++)
      #pragma unroll
      for (int tm = 0; tm < 4; tm++)
        acc[tn][tm] = __builtin_amdgcn_mfma_f32_16x16x32_bf16(af[tn], wf[tm], acc[tn][tm], 0, 0, 0);
  }
  #pragma unroll
  for (int tm = 0; tm < 4; tm++) {
    int col = col0 + c0 + tm*16 + l;
    #pragma unroll
    for (int tn = 0; tn < 4; tn++) {
      #pragma unroll
      for (int r = 0; r < 4; r++) {
        int row = row0 + r0 + tn*16 + qq*4 + r;
        Cb[(size_t)row * 512 + col] = f2bf(acc[tn][tm][r]);
      }
    }
  }
}

// 6) per-window cross attention. block = window (256 thr), wave = head.
__global__ __launch_bounds__(256) void k_attn(const u16* __restrict__ Q,
    const u16* __restrict__ KV, u16* __restrict__ O) {
  __shared__ __align__(16) u16 buf[4][64 * 72];  // per-head: V rows, then P
  int win = blockIdx.x;
  int head = threadIdx.x >> 6, lane = threadIdx.x & 63;
  int qq = lane >> 4, l = lane & 15;
  const u16* Qh = Q  + (size_t)win * 64 * 256 + head * 64;
  const u16* Kh = KV + (size_t)win * 64 * 512 + head * 64;
  const u16* Vh = Kh + 256;
  u16* hb = &buf[head][0];
  // stage V rows: hb[m*72 + d] = V[m][d]  (b128, coalesced, wave-local)
  {
    int mg = lane >> 3, dg = lane & 7;
    #pragma unroll
    for (int i = 0; i < 8; i++) {
      int m = i*8 + mg;
      *(u16x8*)(hb + m*72 + dg*8) = *(const u16x8*)(Vh + (size_t)m*512 + dg*8);
    }
  }
  // transposed V frags -> regs: vf[kbh][td][j] = V[kbh*32+qq*8+j][td*16+l]
  short8 vf[2][4];
  #pragma unroll
  for (int kbh = 0; kbh < 2; kbh++)
    #pragma unroll
    for (int td = 0; td < 4; td++)
      #pragma unroll
      for (int j = 0; j < 8; j++)
        ((u16*)&vf[kbh][td])[j] = hb[(kbh*32 + qq*8 + j)*72 + td*16 + l];
  // QK^T
  floatx4 z = {0.f, 0.f, 0.f, 0.f};
  floatx4 s[4][4];
  #pragma unroll
  for (int a = 0; a < 4; a++)
    #pragma unroll
    for (int b = 0; b < 4; b++) s[a][b] = z;
  #pragma unroll
  for (int kb = 0; kb < 64; kb += 32) {
    short8 af[4], bf[4];
    #pragma unroll
    for (int tn = 0; tn < 4; tn++)
      af[tn] = *(const short8*)(Qh + (size_t)(tn*16 + l) * 256 + kb + qq*8);
    #pragma unroll
    for (int tm = 0; tm < 4; tm++)
      bf[tm] = *(const short8*)(Kh + (size_t)(tm*16 + l) * 512 + kb + qq*8);
    #pragma unroll
    for (int tn = 0; tn < 4; tn++)
      #pragma unroll
      for (int tm = 0; tm < 4; tm++)
        s[tn][tm] = __builtin_amdgcn_mfma_f32_16x16x32_bf16(af[tn], bf[tm], s[tn][tm], 0, 0, 0);
  }
  // softmax rows (over m = tm*16+l, in-thread over tm, cross-lane over l)
  #pragma unroll
  for (int tn = 0; tn < 4; tn++) {
    #pragma unroll
    for (int r = 0; r < 4; r++) {
      float v[4];
      #pragma unroll
      for (int tm = 0; tm < 4; tm++) v[tm] = s[tn][tm][r] * 0.125f;  // hd^-0.5
      float mx = -3.0e38f;
      #pragma unroll
      for (int tm = 0; tm < 4; tm++) mx = fmaxf(mx, v[tm]);
      #pragma unroll
      for (int off = 1; off < 16; off <<= 1) mx = fmaxf(mx, __shfl_xor(mx, off, 64));
      float p0[4], sum = 0.f;
      #pragma unroll
      for (int tm = 0; tm < 4; tm++) { p0[tm] = __expf(v[tm] - mx); sum += p0[tm]; }
      #pragma unroll
      for (int off = 1; off < 16; off <<= 1) sum += __shfl_xor(sum, off, 64);
      float inv = 1.0f / sum;
      int n = tn*16 + qq*4 + r;
      #pragma unroll
      for (int tm = 0; tm < 4; tm++)
        hb[n*72 + tm*16 + l] = f2bf(p0[tm] * inv);   // overwrites V rows (frags in regs)
    }
  }
  // PV
  floatx4 o[4][4];
  #pragma unroll
  for (int a = 0; a < 4; a++)
    #pragma unroll
    for (int b = 0; b < 4; b++) o[a][b] = z;
  #pragma unroll
  for (int kbh = 0; kbh < 2; kbh++) {
    short8 af[4];
    #pragma unroll
    for (int tn = 0; tn < 4; tn++)
      af[tn] = *(const short8*)(hb + (tn*16 + l)*72 + kbh*32 + qq*8);
    #pragma unroll
    for (int tn = 0; tn < 4; tn++)
      #pragma unroll
      for (int td = 0; td < 4; td++)
        o[tn][td] = __builtin_amdgcn_mfma_f32_16x16x32_bf16(af[tn], vf[kbh][td], o[tn][td], 0, 0, 0);
  }
  #pragma unroll
  for (int tn = 0; tn < 4; tn++)
    #pragma unroll
    for (int td = 0; td < 4; td++)
      #pragma unroll
      for (int r = 0; r < 4; r++)
        O[(size_t)(win*64 + tn*16 + qq*4 + r) * 256 + head*64 + td*16 + l] =
            f2bf(o[tn][td][r]);
}

// 7) window_reverse + keep-zeroing + residual add -> xbuf fp32, fused BN stats.
// Heat staged via 8x global_load_lds (linear LDS dest, source chunk-XOR-swizzled
// by pix>>3 so the transposed b16 reads spread banks: 2 lanes/bank = free).
// All 16 feat loads preloaded into regs (latency was the limiter).
__global__ __launch_bounds__(256) void k_reverse(const u16* __restrict__ heat,
    const int* __restrict__ keepf, const float* __restrict__ feat,
    const float* __restrict__ fmask, float* __restrict__ xbuf,
    float* __restrict__ stats) {
  __shared__ __align__(16) u16 lds[64 * 256];   // linear [pix][c-swizzled]
  int bid = blockIdx.x;
  int win = (bid & 7) * 256 + (bid >> 3);
  int b = win >> 8, wh = (win >> 4) & 15, ww = win & 15;
  int h0 = wh * 8, w0 = ww * 8;
  int tid = threadIdx.x;
  int wv = tid >> 6, lane = tid & 63;
  // phase 1: DMA the 32KB contiguous heat window into LDS.
  // call j: wave wv covers pix = j*8 + wv*2 + (lane>>5); lane chunk m = lane&31.
  // source chunk pre-swizzled: m ^ (j&7)  (j == pix>>3 for all lanes of call j)
  {
    const u16* hw = heat + ((size_t)win << 14);
    int m = lane & 31, sub = lane >> 5;
    #pragma unroll
    for (int j = 0; j < 8; j++) {
      int pix = j*8 + wv*2 + sub;
      gl_lds16(hw + pix*256 + ((m ^ j) << 3), lds + (j*8 + wv*2) * 256);
    }
  }
  float kp = keepf[win] ? 1.f : 0.f;
  int hi = tid & 7, cL = tid >> 3;
  int rowoff = (h0 + hi) * 128 + w0;
  float mk[8];
  {
    floatx4 a = *(const floatx4*)(fmask + rowoff);
    floatx4 c = *(const floatx4*)(fmask + rowoff + 4);
    #pragma unroll
    for (int j = 0; j < 4; j++) { mk[j] = a[j]; mk[4 + j] = c[j]; }
  }
  // preload all 16 feat vectors (8 channels x 32B) -> 16 loads in flight
  floatx4 f0[8], f1[8];
  size_t base = (((size_t)(b*256 + cL)) << 14) + rowoff;
  #pragma unroll
  for (int i = 0; i < 8; i++)
    ld2(feat + base + ((size_t)i << 19), f0[i], f1[i]);
  __syncthreads();                              // drains DMA + preloads
  float ls[8], lss[8];
  #pragma unroll
  for (int i = 0; i < 8; i++) {
    int c = i*32 + cL;
    int cS = c ^ (hi << 3);                     // undo source swizzle
    floatx4 o0, o1;
    float s1 = 0.f, s2 = 0.f;
    #pragma unroll
    for (int j = 0; j < 4; j++) {
      o0[j] = kp * bf2f(lds[(hi*8 + j)*256 + cS])     + f0[i][j] * mk[j];
      o1[j] = kp * bf2f(lds[(hi*8 + j + 4)*256 + cS]) + f1[i][j] * mk[4 + j];
      s1 += o0[j] + o1[j];
      s2 += o0[j]*o0[j] + o1[j]*o1[j];
    }
    size_t goff = base + ((size_t)i << 19);
    *(floatx4*)(xbuf + goff)     = o0;
    *(floatx4*)(xbuf + goff + 4) = o1;
    ls[i] = s1; lss[i] = s2;
  }
  // deferred reduction over the 8 pixel-rows (lanes differ in bits 0..2 = hi)
  #pragma unroll
  for (int i = 0; i < 8; i++) {
    #pragma unroll
    for (int off = 1; off < 8; off <<= 1) {
      ls[i]  += __shfl_xor(ls[i],  off, 64);
      lss[i] += __shfl_xor(lss[i], off, 64);
    }
  }
  if (hi == 0) {
    #pragma unroll
    for (int i = 0; i < 8; i++) {
      atomicAdd(&stats[i*32 + cL],       ls[i]);
      atomicAdd(&stats[256 + i*32 + cL], lss[i]);
    }
  }
}

// 9) fold mean/var/gamma/beta into per-channel scale+shift.
__global__ void k_scaleshift(const float* __restrict__ stats,
                             const float* __restrict__ gamma,
                             const float* __restrict__ beta,
                             float* __restrict__ scsh) {
  int c = threadIdx.x;
  const float invN = 1.0f / 131072.0f;
  float mean = stats[c] * invN;
  float var  = stats[256 + c] * invN - mean * mean;
  float sc = gamma[c] * rsqrtf(var + 1e-5f);
  scsh[c] = sc;
  scsh[256 + c] = beta[c] - mean * sc;
}

// 10) normalize in-place (xbuf == out, fp32).
__global__ __launch_bounds__(256) void k_norm(float* __restrict__ xbuf,
                                              const float* __restrict__ scsh) {
  size_t e = ((size_t)blockIdx.x * 256 + threadIdx.x) * 4;
  int c = (int)((e >> 14) & 255);
  float sc = scsh[c], sh = scsh[256 + c];
  floatx4 v4 = *(const floatx4*)(xbuf + e);
  #pragma unroll
  for (int j = 0; j < 4; j++) v4[j] = v4[j] * sc + sh;
  *(floatx4*)(xbuf + e) = v4;
}

extern "C" void kernel_launch(void* const* d_in, const int* in_sizes, int n_in,
                              void* d_out, int out_size, void* d_ws, size_t ws_size,
                              hipStream_t stream) {
  (void)in_sizes; (void)n_in; (void)out_size; (void)ws_size;
  const float* pre    = (const float*)d_in[0];
  const float* pmask  = (const float*)d_in[1];
  const float* feat   = (const float*)d_in[2];
  const float* fmask  = (const float*)d_in[3];
  const float* maskin = (const float*)d_in[4];
  const float* q_w    = (const float*)d_in[5];
  const float* kv_w   = (const float*)d_in[6];
  const float* proj_w = (const float*)d_in[7];
  const float* proj_b = (const float*)d_in[8];
  const float* gamma  = (const float*)d_in[9];
  const float* beta   = (const float*)d_in[10];
  float* out = (float*)d_out;

  const size_t NE = 33554432;                 // 131072 x 256
  u16* Xw = (u16*)d_ws;                       // staging X; later attention O
  u16* Tw = Xw + NE;                          // staging T; later heat
  u16* Qb = Tw + NE;                          // Q
  u16* KV = Qb + NE;                          // row-major [131072][512]: K | V
  u16* Wb = KV + 2*NE;                        // bf16 weights: q(65536) kv(131072) proj(65536)
  float* E     = (float*)(Wb + 262144);       // 131072 floats
  int*   keepf = (int*)(E + 131072);          // 2048 ints
  float* stats = (float*)(keepf + 2048);      // sum[256], sumsq[256]
  float* scsh  = stats + 512;                 // scale[256], shift[256]

  hipMemsetAsync(stats, 0, 2048, stream);
  k_cvtw<<<1024, 256, 0, stream>>>(q_w, kv_w, proj_w, Wb);
  k_interp<<<512, 256, 0, stream>>>(maskin, fmask, E);
  k_keep<<<2048, 64, 0, stream>>>(E, keepf);
  k_stage<<<2048, 256, 0, stream>>>(feat, fmask, pre, pmask, E, Xw, Tw);
  k_gemm128n<<<2048, 256, 0, stream>>>(Xw, Wb, nullptr, Qb);
  k_gemm128kv<<<4096, 256, 0, stream>>>(Tw, Wb + 65536, KV);
  k_attn<<<2048, 256, 0, stream>>>(Qb, KV, Xw /*O (Xw dead)*/);
  k_gemm128n<<<2048, 256, 0, stream>>>(Xw /*O*/, Wb + 196608, proj_b, Tw /*heat*/);
  k_reverse<<<2048, 256, 0, stream>>>(Tw /*heat*/, keepf, feat, fmask,
                                      out /*xbuf fp32*/, stats);
  k_scaleshift<<<1, 256, 0, stream>>>(stats, gamma, beta, scsh);
  k_norm<<<32768, 256, 0, stream>>>(out, scsh);
}